// Round 13
// baseline (493.394 us; speedup 1.0000x reference)
//
#include <hip/hip_runtime.h>
#include <hip/hip_bf16.h>
#include <hip/hip_cooperative_groups.h>

namespace cg = cooperative_groups;

// ---------------------------------------------------------------------------
// DJconv as ONE cooperative kernel, 11 phases with grid.sync() between:
//  1 pack_rows  2 bitT(H)  3 csr_build  4 g2_or(CSR)  5 b2_or(CSR)+rsB
//  6 bitT(B2)  7 degrees+scale+transpose  8 skinny hop1 (SAME-X, 2 acc)
//  9 reduce_T  10 skinny hop2 (two-pass, 1 acc)  11 final GEMM
// Phase bodies transcribed from the validated round-11 kernels.
// ---------------------------------------------------------------------------

#define NUu 4096
#define NIi 3072
#define NWI 96
#define NWU 128
#define LSTR 128
#define SKs 8
#define NBI (NIi / 64)    // 48
#define NBU (NUu / 64)    // 64
#define NTILE (NBI + NBU) // 112

typedef unsigned short u16;
typedef unsigned int u32;
typedef unsigned long long u64;
typedef __attribute__((ext_vector_type(8))) short bf16x8_t;
typedef __attribute__((ext_vector_type(4))) float f32x4_t;
typedef __attribute__((ext_vector_type(4))) unsigned int u32x4_t;

__device__ __forceinline__ float bf2f(u16 u) {
    union { float f; unsigned int i; } x; x.i = ((unsigned int)u) << 16; return x.f;
}
__device__ __forceinline__ u16 f2bf(float f) {
    union { float f; unsigned int i; } x; x.f = f;
    unsigned int r = x.i + 0x7FFFu + ((x.i >> 16) & 1u);
    return (u16)(r >> 16);
}
__device__ __forceinline__ void gload16(const void* g, void* l) {
    __builtin_amdgcn_global_load_lds(
        (const __attribute__((address_space(1))) void*)g,
        (__attribute__((address_space(3))) void*)l, 16, 0, 0);
}

struct Prm {
    const float *H, *U, *I, *W, *bs;
    float *Uout, *Iout;
    u32 *Hbits, *HbitsT, *G2bits, *B2bits, *B2bitsT;
    u16 *itemsU, *usersI;
    u32 *cntU, *cntI;
    float *rsB;
    float *dvu, *D3, *D4, *dvi, *D1, *D2;
    u16 *XuT, *XiT, *TaT, *TbT, *SaT, *SbT;
    u16 *partI, *partU;
};

__global__ __launch_bounds__(256)
void mega(Prm p)
{
    __shared__ __align__(16) char lds[33024];
    cg::grid_group grid = cg::this_grid();
    const int tid = threadIdx.x;
    const int bid = blockIdx.x;
    const int nb  = gridDim.x;
    const int tx = tid & 63, ty = tid >> 6;

    // ---- P1: pack H rows to bits (streaming, 1 thread per u32 word) -------
    for (int idx = bid * 256 + tid; idx < NUu * NWI; idx += nb * 256) {
        const float4* fp = (const float4*)(p.H + (size_t)idx * 32);
        u32 m = 0;
#pragma unroll
        for (int r = 0; r < 8; ++r) {
            float4 v = fp[r];
            m |= (v.x >= 0.5f ? 1u : 0u) << (r * 4 + 0);
            m |= (v.y >= 0.5f ? 1u : 0u) << (r * 4 + 1);
            m |= (v.z >= 0.5f ? 1u : 0u) << (r * 4 + 2);
            m |= (v.w >= 0.5f ? 1u : 0u) << (r * 4 + 3);
        }
        p.Hbits[idx] = m;
    }
    grid.sync();

    // ---- P2: HbitsT = bit-transpose(Hbits) ---------------------------------
    {
        u32* s32 = (u32*)lds;
        for (int vb = bid; vb < NBI * NBU; vb += nb) {
            const int c0 = (vb % NBI) * 64, r0 = (vb / NBI) * 64;
            if (tid < 128)
                s32[tid] = p.Hbits[(size_t)(r0 + (tid >> 1)) * NWI + (c0 >> 5) + (tid & 1)];
            __syncthreads();
#pragma unroll
            for (int i = 0; i < 16; ++i) {
                int j = i * 4 + ty;
                u32 word = s32[tx * 2 + (j >> 5)];
                u64 mm = __ballot(((word >> (j & 31)) & 1u) != 0);
                if (tx == 0) {
                    p.HbitsT[(size_t)(c0 + j) * NWU + (r0 >> 5)]     = (u32)mm;
                    p.HbitsT[(size_t)(c0 + j) * NWU + (r0 >> 5) + 1] = (u32)(mm >> 32);
                }
            }
            __syncthreads();
        }
    }
    grid.sync();

    // ---- P3: CSR lists + counts, both sides, atomic-free -------------------
    for (int vb = bid; vb < NUu / 4 + NIi / 4; vb += nb) {
        const u32* bits; u16* list; u32* cnt; int nw, row;
        if (vb < NUu / 4) { bits = p.Hbits;  list = p.itemsU; cnt = p.cntU; nw = NWI; row = vb * 4; }
        else { bits = p.HbitsT; list = p.usersI; cnt = p.cntI; nw = NWU; row = (vb - NUu / 4) * 4; }
        row += ty;
        const int lane = tx;
        u32 total = 0;
        u16* lp = list + (size_t)row * LSTR;
        for (int rnd = 0; rnd * 64 < nw; ++rnd) {
            int w = rnd * 64 + lane;
            u32 word = (w < nw) ? bits[(size_t)row * nw + w] : 0u;
            u32 pc = __popc(word);
            u32 pre = pc;
#pragma unroll
            for (int off = 1; off < 64; off <<= 1) {
                u32 tt = (u32)__shfl_up((int)pre, off);
                if (lane >= off) pre += tt;
            }
            u32 excl = pre - pc + total;
            while (word) {
                int b = __ffs(word) - 1;
                word &= word - 1;
                if (excl < LSTR) lp[excl] = (u16)(w * 32 + b);
                ++excl;
            }
            total += (u32)__shfl((int)pre, 63);
        }
        if (lane == 0) cnt[row] = total;
    }
    grid.sync();

    // ---- P4: G2 = (HtH > 0) via CSR (2 rows per block) ---------------------
    for (int vb = bid; vb < NIi / 2; vb += nb) {
        const int g = tid >> 7, w = tid & 127;
        const int i = vb * 2 + g;
        u32 n = p.cntI[i]; if (n > LSTR) n = LSTR;
        const u16* lp = p.usersI + (size_t)i * LSTR;
        u32 acc = 0;
        for (u32 k = 0; k < n; ++k) {
            int u = lp[k];
            if (w < NWI) acc |= p.Hbits[(size_t)u * NWI + w];
        }
        if (w < NWI) p.G2bits[(size_t)i * NWI + w] = acc;
    }
    grid.sync();

    // ---- P5: B2 = (H G2 > 0) via CSR + rsB popcount (2 rows per block) -----
    {
        u32* ps = (u32*)lds;
        for (int vb = bid; vb < NUu / 2; vb += nb) {
            const int g = tid >> 7, w = tid & 127;
            const int u = vb * 2 + g;
            u32 n = p.cntU[u]; if (n > LSTR) n = LSTR;
            const u16* lp = p.itemsU + (size_t)u * LSTR;
            u32 acc = 0;
            for (u32 k = 0; k < n; ++k) {
                int i = lp[k];
                if (w < NWI) acc |= p.G2bits[(size_t)i * NWI + w];
            }
            if (w < NWI) p.B2bits[(size_t)u * NWI + w] = acc;
            ps[tid] = (w < NWI) ? (u32)__popc(acc) : 0u;
            __syncthreads();
            if (w < 64) {
                u32 s = ps[g * 128 + w] + ps[g * 128 + w + 64];
#pragma unroll
                for (int off = 32; off; off >>= 1) s += (u32)__shfl_down((int)s, off);
                if (w == 0) p.rsB[u] = (float)s;
            }
            __syncthreads();
        }
    }
    grid.sync();

    // ---- P6: B2bitsT = bit-transpose(B2bits) -------------------------------
    {
        u32* s32 = (u32*)lds;
        for (int vb = bid; vb < NBI * NBU; vb += nb) {
            const int c0 = (vb % NBI) * 64, r0 = (vb / NBI) * 64;
            if (tid < 128)
                s32[tid] = p.B2bits[(size_t)(r0 + (tid >> 1)) * NWI + (c0 >> 5) + (tid & 1)];
            __syncthreads();
#pragma unroll
            for (int i = 0; i < 16; ++i) {
                int j = i * 4 + ty;
                u32 word = s32[tx * 2 + (j >> 5)];
                u64 mm = __ballot(((word >> (j & 31)) & 1u) != 0);
                if (tx == 0) {
                    p.B2bitsT[(size_t)(c0 + j) * NWU + (r0 >> 5)]     = (u32)mm;
                    p.B2bitsT[(size_t)(c0 + j) * NWU + (r0 >> 5) + 1] = (u32)(mm >> 32);
                }
            }
            __syncthreads();
        }
    }
    grid.sync();

    // ---- P7: degrees + scale + transpose -----------------------------------
    {
        u16 (*t)[65] = (u16(*)[65])lds;          // 8320 B
        float* dvl   = (float*)(lds + 8320);     // 256 B
        u32*  pcs    = (u32*)(lds + 8576);       // 1024 B
        for (int vb = bid; vb < NTILE; vb += nb) {
            const float* X; u16* outT; int M, m0;
            if (vb < NBU) {
                m0 = vb * 64;
                if (tid < 64) {
                    float a = (float)p.cntU[m0 + tid], b = p.rsB[m0 + tid], tt = a + b;
                    float dv = tt > 0.f ? 1.0f / sqrtf(tt) : 0.f;
                    p.dvu[m0 + tid] = dv;
                    p.D3[m0 + tid]  = a > 0.f ? 1.0f / a : 0.f;
                    p.D4[m0 + tid]  = b > 0.f ? 1.0f / b : 0.f;
                    dvl[tid] = dv;
                }
                X = p.U; outT = p.XuT; M = NUu;
            } else {
                m0 = (vb - NBU) * 64;
                {
                    int r = tid >> 2, q = tid & 3;
                    const u32* rb = p.B2bitsT + (size_t)(m0 + r) * NWU + q * 32;
                    u32 sb = 0;
                    for (int k = 0; k < 32; ++k) sb += __popc(rb[k]);
                    pcs[r * 4 + q] = sb;
                }
                __syncthreads();
                if (tid < 64) {
                    float b = (float)(pcs[tid * 4] + pcs[tid * 4 + 1] + pcs[tid * 4 + 2] + pcs[tid * 4 + 3]);
                    float a = (float)p.cntI[m0 + tid], tt = a + b;
                    float dv = tt > 0.f ? 1.0f / sqrtf(tt) : 0.f;
                    p.dvi[m0 + tid] = dv;
                    p.D1[m0 + tid]  = a > 0.f ? 1.0f / a : 0.f;
                    p.D2[m0 + tid]  = b > 0.f ? 1.0f / b : 0.f;
                    dvl[tid] = dv;
                }
                X = p.I; outT = p.XiT; M = NIi;
            }
            __syncthreads();
#pragma unroll
            for (int i = 0; i < 16; ++i) {
                int row = i * 4 + ty;
                t[row][tx] = f2bf(X[(size_t)(m0 + row) * 64 + tx] * dvl[row]);
            }
            __syncthreads();
#pragma unroll
            for (int i = 0; i < 16; ++i) {
                int d = i * 4 + ty;
                outT[(size_t)d * M + m0 + tx] = t[tx][d];
            }
            __syncthreads();
        }
    }
    grid.sync();

    // ---- P8: skinny hop1 (shared X, two accumulators) ----------------------
    {
        char (*lB)[16384] = (char(*)[16384])lds;   // 32 KB
        const int lane = tid & 63, w = tid >> 6;
        const int q8 = (lane >> 4) * 8;
        const int rd15 = lane & 15;
        const int swz = (rd15 & 7) << 4;
        const int cb = (lane >> 4) * 16;
        const int st_row = tid >> 4;
        const int st_colb = (tid & 15) * 16;
        for (int vb = bid; vb < NTILE * SKs; vb += nb) {
            const int bx = vb % NTILE, sk = vb / NTILE;
            const u32* MbA; const u32* MbBm; const u16* Xa; u16* part;
            int M, K, nw, m0;
            if (bx < NBI) { M = NIi; K = NUu; nw = NWU; m0 = bx * 64;
                MbA = p.HbitsT; MbBm = p.B2bitsT; Xa = p.XuT; part = p.partI; }
            else { M = NUu; K = NIi; nw = NWI; m0 = (bx - NBI) * 64;
                MbA = p.Hbits; MbBm = p.B2bits; Xa = p.XiT; part = p.partU; }
            const int Kb = K / SKs, kBeg = sk * Kb, nc = Kb >> 7;
            const char* Xac = (const char*)Xa;
            const size_t rowstride = (size_t)K * 2;
            f32x4_t accH[4], accB[4];
#pragma unroll
            for (int j = 0; j < 4; ++j) {
                accH[j] = (f32x4_t){0.f, 0.f, 0.f, 0.f};
                accB[j] = (f32x4_t){0.f, 0.f, 0.f, 0.f};
            }
            const u32* rwH = MbA  + (size_t)(m0 + w * 16 + rd15) * nw + (kBeg >> 5);
            const u32* rwB = MbBm + (size_t)(m0 + w * 16 + rd15) * nw + (kBeg >> 5);
            auto STG = [&](int buf, int c) {
                size_t kb2 = ((size_t)kBeg + (size_t)c * 128) * 2;
#pragma unroll
                for (int r = 0; r < 4; ++r) {
                    int row = r * 16 + st_row;
                    int scol = st_colb ^ ((row & 7) << 4);
                    gload16(Xac + (size_t)row * rowstride + kb2 + scol,
                            &lB[buf][r * 4096 + tid * 16]);
                }
            };
            STG(0, 0);
            __syncthreads();
            for (int c = 0; c < nc; ++c) {
                const int buf = c & 1;
                if (c + 1 < nc) STG(buf ^ 1, c + 1);
                u32x4_t wvH = *(const u32x4_t*)(rwH + c * 4);
                u32x4_t wvB = *(const u32x4_t*)(rwB + c * 4);
#pragma unroll
                for (int s = 0; s < 4; ++s) {
                    u32 byH = (wvH[s] >> q8) & 0xffu;
                    u32 byB = (wvB[s] >> q8) & 0xffu;
                    union { bf16x8_t v; u32 w[4]; } aH, aB;
#pragma unroll
                    for (int i = 0; i < 4; ++i) {
                        aH.w[i] = (((byH >> (2 * i)) & 1u) ? 0x3F80u : 0u)
                                | (((byH >> (2 * i + 1)) & 1u) ? 0x3F800000u : 0u);
                        aB.w[i] = (((byB >> (2 * i)) & 1u) ? 0x3F80u : 0u)
                                | (((byB >> (2 * i + 1)) & 1u) ? 0x3F800000u : 0u);
                    }
#pragma unroll
                    for (int j = 0; j < 4; ++j) {
                        int off = (rd15 + j * 16) * 256 + ((s * 64 + cb) ^ swz);
                        bf16x8_t b0 = *(const bf16x8_t*)(&lB[buf][off]);
                        accH[j] = __builtin_amdgcn_mfma_f32_16x16x32_bf16(aH.v, b0, accH[j], 0, 0, 0);
                        accB[j] = __builtin_amdgcn_mfma_f32_16x16x32_bf16(aB.v, b0, accB[j], 0, 0, 0);
                    }
                }
                __syncthreads();
            }
            const int rg = (lane >> 4) * 4;
            u16* oH = part + ((size_t)sk * M + m0 + w * 16 + rg) * 64;
            u16* oB = part + ((size_t)(SKs + sk) * M + m0 + w * 16 + rg) * 64;
#pragma unroll
            for (int j = 0; j < 4; ++j)
#pragma unroll
                for (int r = 0; r < 4; ++r) {
                    oH[(size_t)r * 64 + j * 16 + rd15] = f2bf(accH[j][r]);
                    oB[(size_t)r * 64 + j * 16 + rd15] = f2bf(accB[j][r]);
                }
        }
    }
    grid.sync();

    // ---- P9: reduce hop1 partials -> TaT/TbT/SaT/SbT ------------------------
    {
        u16 (*t)[65] = (u16(*)[65])lds;
        for (int vb = bid; vb < NTILE * 2; vb += nb) {
            const int bx = vb % NTILE, z = vb / NTILE;
            const u16* part; const float* rs; u16* out; int M, m0;
            if (bx < NBI) { M = NIi; m0 = bx * 64; part = p.partI;
                rs = z ? p.D2 : p.D1; out = z ? p.TbT : p.TaT; }
            else { M = NUu; m0 = (bx - NBI) * 64; part = p.partU;
                rs = z ? p.D4 : p.D3; out = z ? p.SbT : p.SaT; }
#pragma unroll
            for (int i = 0; i < 16; ++i) {
                int row = i * 4 + ty;
                int m = m0 + row;
                float s = 0.f;
#pragma unroll
                for (int sk = 0; sk < SKs; ++sk)
                    s += bf2f(part[((size_t)(z * SKs + sk) * M + m) * 64 + tx]);
                t[row][tx] = f2bf(s * rs[m]);
            }
            __syncthreads();
#pragma unroll
            for (int i = 0; i < 16; ++i) {
                int d = i * 4 + ty;
                out[(size_t)d * M + m0 + tx] = t[tx][d];
            }
            __syncthreads();
        }
    }
    grid.sync();

    // ---- P10: skinny hop2 (two passes, one accumulator, 32 KB LDS) ---------
    {
        char (*lB)[16384] = (char(*)[16384])lds;
        const int lane = tid & 63, w = tid >> 6;
        const int q8 = (lane >> 4) * 8;
        const int rd15 = lane & 15;
        const int swz = (rd15 & 7) << 4;
        const int cb = (lane >> 4) * 16;
        const int st_row = tid >> 4;
        const int st_colb = (tid & 15) * 16;
        for (int vb = bid; vb < NTILE * SKs; vb += nb) {
            const int bx = vb % NTILE, sk = vb / NTILE;
            const u32* Mb0; const u32* Mb1; const u16* X0; const u16* X1; u16* part;
            int M, K, nw, m0;
            if (bx < NBI) { M = NIi; K = NUu; nw = NWU; m0 = bx * 64;
                Mb0 = p.HbitsT; Mb1 = p.B2bitsT; X0 = p.SaT; X1 = p.SbT; part = p.partI; }
            else { M = NUu; K = NIi; nw = NWI; m0 = (bx - NBI) * 64;
                Mb0 = p.Hbits; Mb1 = p.B2bits; X0 = p.TaT; X1 = p.TbT; part = p.partU; }
            const int Kb = K / SKs, kBeg = sk * Kb, nc = Kb >> 7;
            const size_t rowstride = (size_t)K * 2;
            f32x4_t acc[4];
#pragma unroll
            for (int j = 0; j < 4; ++j) acc[j] = (f32x4_t){0.f, 0.f, 0.f, 0.f};
            for (int pass = 0; pass < 2; ++pass) {
                const u32* Mb = pass ? Mb1 : Mb0;
                const char* Xc = (const char*)(pass ? X1 : X0);
                const u32* rw = Mb + (size_t)(m0 + w * 16 + rd15) * nw + (kBeg >> 5);
                auto STG = [&](int buf, int c) {
                    size_t kb2 = ((size_t)kBeg + (size_t)c * 128) * 2;
#pragma unroll
                    for (int r = 0; r < 4; ++r) {
                        int row = r * 16 + st_row;
                        int scol = st_colb ^ ((row & 7) << 4);
                        gload16(Xc + (size_t)row * rowstride + kb2 + scol,
                                &lB[buf][r * 4096 + tid * 16]);
                    }
                };
                STG(0, 0);
                __syncthreads();
                for (int c = 0; c < nc; ++c) {
                    const int buf = c & 1;
                    if (c + 1 < nc) STG(buf ^ 1, c + 1);
                    u32x4_t wv = *(const u32x4_t*)(rw + c * 4);
#pragma unroll
                    for (int s = 0; s < 4; ++s) {
                        u32 by = (wv[s] >> q8) & 0xffu;
                        union { bf16x8_t v; u32 w[4]; } a;
#pragma unroll
                        for (int i = 0; i < 4; ++i)
                            a.w[i] = (((by >> (2 * i)) & 1u) ? 0x3F80u : 0u)
                                   | (((by >> (2 * i + 1)) & 1u) ? 0x3F800000u : 0u);
#pragma unroll
                        for (int j = 0; j < 4; ++j) {
                            int off = (rd15 + j * 16) * 256 + ((s * 64 + cb) ^ swz);
                            bf16x8_t b0 = *(const bf16x8_t*)(&lB[buf][off]);
                            acc[j] = __builtin_amdgcn_mfma_f32_16x16x32_bf16(a.v, b0, acc[j], 0, 0, 0);
                        }
                    }
                    __syncthreads();
                }
            }
            const int rg = (lane >> 4) * 4;
            u16* o = part + ((size_t)sk * M + m0 + w * 16 + rg) * 64;
#pragma unroll
            for (int j = 0; j < 4; ++j)
#pragma unroll
                for (int r = 0; r < 4; ++r)
                    o[(size_t)r * 64 + j * 16 + rd15] = f2bf(acc[j][r]);
        }
    }
    grid.sync();

    // ---- P11: fused reduce + final GEMM ------------------------------------
    {
        float* Wl = (float*)lds;                       // 16384 B
        float (*Zl)[65] = (float(*)[65])(lds + 16384); // 16640 B
        for (int vb = bid; vb < NTILE; vb += nb) {
            const u16* part; const float* X0; const float* dv; float* out; int M, m0;
            if (vb < NBU) { M = NUu; m0 = vb * 64; part = p.partU; X0 = p.U; dv = p.dvu; out = p.Uout; }
            else { M = NIi; m0 = (vb - NBU) * 64; part = p.partI; X0 = p.I; dv = p.dvi; out = p.Iout; }
            for (int i = tid; i < 4096; i += 256) Wl[i] = p.W[i];
            for (int r = ty; r < 64; r += 4) {
                int m = m0 + r;
                float s = 0.f;
#pragma unroll
                for (int s8 = 0; s8 < SKs; ++s8)
                    s += bf2f(part[((size_t)s8 * M + m) * 64 + tx]);
                Zl[r][tx] = dv[m] * s + X0[(size_t)m * 64 + tx];
            }
            __syncthreads();
            float acc[16];
#pragma unroll
            for (int rr = 0; rr < 16; ++rr) acc[rr] = 0.f;
            for (int e = 0; e < 64; ++e) {
                float wv = Wl[e * 64 + tx];
#pragma unroll
                for (int rr = 0; rr < 16; ++rr)
                    acc[rr] += Zl[ty * 16 + rr][e] * wv;
            }
            float bv = p.bs[tx];
#pragma unroll
            for (int rr = 0; rr < 16; ++rr)
                out[(size_t)(m0 + ty * 16 + rr) * 64 + tx] = acc[rr] + bv;
            __syncthreads();
        }
    }
}

extern "C" void kernel_launch(void* const* d_in, const int* in_sizes, int n_in,
                              void* d_out, int out_size, void* d_ws, size_t ws_size,
                              hipStream_t stream)
{
    (void)in_sizes; (void)n_in; (void)out_size;
    Prm p;
    p.H  = (const float*)d_in[0];
    p.U  = (const float*)d_in[1];
    p.I  = (const float*)d_in[2];
    p.W  = (const float*)d_in[3];
    p.bs = (const float*)d_in[4];
    p.Uout = (float*)d_out;
    p.Iout = (float*)d_out + (size_t)NUu * 64;

    char* ws = (char*)d_ws;
    size_t off = 0;
    auto alloc = [&](size_t bytes) -> char* {
        char* q = ws + off;
        off += (bytes + 255) & ~(size_t)255;
        return q;
    };
    p.Hbits   = (u32*)alloc((size_t)NUu * NWI * 4);
    p.HbitsT  = (u32*)alloc((size_t)NIi * NWU * 4);
    p.G2bits  = (u32*)alloc((size_t)NIi * NWI * 4);
    p.B2bits  = (u32*)alloc((size_t)NUu * NWI * 4);
    p.B2bitsT = (u32*)alloc((size_t)NIi * NWU * 4);
    p.itemsU  = (u16*)alloc((size_t)NUu * LSTR * 2);
    p.usersI  = (u16*)alloc((size_t)NIi * LSTR * 2);
    p.partU   = (u16*)alloc((size_t)2 * SKs * NUu * 64 * 2);
    p.partI   = (u16*)alloc((size_t)2 * SKs * NIi * 64 * 2);
    p.XuT = (u16*)alloc((size_t)64 * NUu * 2);
    p.XiT = (u16*)alloc((size_t)64 * NIi * 2);
    p.TaT = (u16*)alloc((size_t)64 * NIi * 2);
    p.TbT = (u16*)alloc((size_t)64 * NIi * 2);
    p.SaT = (u16*)alloc((size_t)64 * NUu * 2);
    p.SbT = (u16*)alloc((size_t)64 * NUu * 2);
    p.cntU = (u32*)alloc(NUu * 4);
    p.cntI = (u32*)alloc(NIi * 4);
    p.rsB  = (float*)alloc(NUu * 4);
    p.dvu = (float*)alloc(NUu * 4);
    p.D3  = (float*)alloc(NUu * 4);
    p.D4  = (float*)alloc(NUu * 4);
    p.dvi = (float*)alloc(NIi * 4);
    p.D1  = (float*)alloc(NIi * 4);
    p.D2  = (float*)alloc(NIi * 4);
    if (off > ws_size) return;  // workspace too small: fail loudly

    int maxb = 0;
    if (hipOccupancyMaxActiveBlocksPerMultiprocessor(&maxb, (const void*)mega, 256, 0)
            != hipSuccess || maxb < 1)
        maxb = 2;
    int grid = maxb * 256;            // 256 CUs on MI355X
    if (grid > 1024) grid = 1024;     // >= all virtual-block counts' parallel needs

    void* args[] = { &p };
    hipLaunchCooperativeKernel((const void*)mega, dim3(grid), dim3(256), args, 0, stream);
}

// Round 14
// 134.291 us; speedup vs baseline: 3.6741x; 3.6741x over previous
//
#include <hip/hip_runtime.h>
#include <hip/hip_bf16.h>

// ---------------------------------------------------------------------------
// DJconv: all binary matrices (H, G2=(HᵀH>0), B2=(H·G2>0)) stay BIT-PACKED.
//   user: Zu = H·(D1·HᵀXu) + B2·(D2·B2ᵀXu);  Uout = (dvu⊙Zu + U)W + b
//   item: Zi = Hᵀ·(D3·HXi) + B2ᵀ·(D4·B2Xi);  Iout = (dvi⊙Zi + I)W + b
// 11-kernel chain (round-11 structure + degrees fused into scale_transpose):
//  pack_rows -> bitT(H) -> csr_build2 -> g2_or(CSR) -> b2_or(CSR)+rsB
//  -> bitT(B2) -> scale_transpose_deg -> skinny4<1> -> reduce_T2
//  -> skinny4<0> -> final2.   Partials bf16 (validated r10/r11).
// Round-13 lesson: grid.sync() on 8-XCD MI355X >> kernel boundary; never
// single-kernel-ize this chain.
// ---------------------------------------------------------------------------

#define NUu 4096
#define NIi 3072
#define NWI 96            // item-bit words per user-row  (3072/32)
#define NWU 128           // user-bit words per item-row  (4096/32)
#define LSTR 128          // CSR stride (mean deg 15/20; 128 >> max)
#define SKs 8
#define NBI (NIi / 64)    // 48
#define NBU (NUu / 64)    // 64

typedef unsigned short u16;
typedef unsigned int u32;
typedef unsigned long long u64;
typedef __attribute__((ext_vector_type(8))) short bf16x8_t;
typedef __attribute__((ext_vector_type(4))) float f32x4_t;
typedef __attribute__((ext_vector_type(4))) unsigned int u32x4_t;

__device__ __forceinline__ float bf2f(u16 u) {
    union { float f; unsigned int i; } x; x.i = ((unsigned int)u) << 16; return x.f;
}
__device__ __forceinline__ u16 f2bf(float f) {
    union { float f; unsigned int i; } x; x.f = f;
    unsigned int r = x.i + 0x7FFFu + ((x.i >> 16) & 1u);
    return (u16)(r >> 16);
}
__device__ __forceinline__ void gload16(const void* g, void* l) {
    __builtin_amdgcn_global_load_lds(
        (const __attribute__((address_space(1))) void*)g,
        (__attribute__((address_space(3))) void*)l, 16, 0, 0);
}

// --- H f32 -> packed bits, one thread per u32 word (streaming, no sync) ----
__global__ __launch_bounds__(256)
void pack_rows(const float* __restrict__ H, u32* __restrict__ Hbits)
{
    const int gid = blockIdx.x * 256 + threadIdx.x;   // NUu*NWI threads
    const float4* p = (const float4*)(H + (size_t)gid * 32);
    u32 m = 0;
#pragma unroll
    for (int r = 0; r < 8; ++r) {
        float4 v = p[r];
        m |= (v.x >= 0.5f ? 1u : 0u) << (r * 4 + 0);
        m |= (v.y >= 0.5f ? 1u : 0u) << (r * 4 + 1);
        m |= (v.z >= 0.5f ? 1u : 0u) << (r * 4 + 2);
        m |= (v.w >= 0.5f ? 1u : 0u) << (r * 4 + 3);
    }
    Hbits[gid] = m;
}

// --- generic 64x64-tile bit transpose via ballot ----------------------------
__global__ __launch_bounds__(256)
void bit_transpose(const u32* __restrict__ in, u32* __restrict__ out,
                   int nwIn, int nwOut)
{
    __shared__ u32 s32[128];
    const int tx = threadIdx.x, ty = threadIdx.y;
    const int c0 = blockIdx.x * 64, r0 = blockIdx.y * 64;
    const int t = ty * 64 + tx;
    if (t < 128) s32[t] = in[(size_t)(r0 + (t >> 1)) * nwIn + (c0 >> 5) + (t & 1)];
    __syncthreads();
#pragma unroll
    for (int i = 0; i < 16; ++i) {
        int j = i * 4 + ty;
        u32 word = s32[tx * 2 + (j >> 5)];
        u64 mm = __ballot(((word >> (j & 31)) & 1u) != 0);
        if (tx == 0) {
            out[(size_t)(c0 + j) * nwOut + (r0 >> 5)]     = (u32)mm;
            out[(size_t)(c0 + j) * nwOut + (r0 >> 5) + 1] = (u32)(mm >> 32);
        }
    }
}

// --- CSR lists + row counts from packed bits, wave per row, atomic-free -----
__global__ __launch_bounds__(256)
void csr_build2(const u32* __restrict__ Hbits, const u32* __restrict__ HbitsT,
                u16* __restrict__ itemsU, u16* __restrict__ usersI,
                u32* __restrict__ cntU, u32* __restrict__ cntI)
{
    const int bx = blockIdx.x;
    const u32* bits; u16* list; u32* cnt; int nw, row;
    if (bx < NUu / 4) { bits = Hbits;  list = itemsU; cnt = cntU; nw = NWI; row = bx * 4; }
    else { bits = HbitsT; list = usersI; cnt = cntI; nw = NWU; row = (bx - NUu / 4) * 4; }
    row += (threadIdx.x >> 6);
    const int lane = threadIdx.x & 63;
    u32 total = 0;
    u16* lp = list + (size_t)row * LSTR;
    for (int rnd = 0; rnd * 64 < nw; ++rnd) {
        int w = rnd * 64 + lane;
        u32 word = (w < nw) ? bits[(size_t)row * nw + w] : 0u;
        u32 pc = __popc(word);
        u32 pre = pc;                              // inclusive scan
#pragma unroll
        for (int off = 1; off < 64; off <<= 1) {
            u32 tt = (u32)__shfl_up((int)pre, off);
            if (lane >= off) pre += tt;
        }
        u32 excl = pre - pc + total;
        while (word) {
            int b = __ffs(word) - 1;
            word &= word - 1;
            if (excl < LSTR) lp[excl] = (u16)(w * 32 + b);
            ++excl;
        }
        total += (u32)__shfl((int)pre, 63);
    }
    if (lane == 0) cnt[row] = total;
}

// --- G2 row i = OR over users(i) of H bit-rows ------------------------------
__global__ __launch_bounds__(128)
void g2_or(const u32* __restrict__ Hbits, const u16* __restrict__ usersI,
           const u32* __restrict__ cntI, u32* __restrict__ G2bits)
{
    const int i = blockIdx.x;
    const int w = threadIdx.x;
    u32 n = cntI[i]; if (n > LSTR) n = LSTR;
    u32 acc = 0;
    for (u32 k = 0; k < n; ++k) {
        int u = usersI[i * LSTR + k];
        if (w < NWI) acc |= Hbits[u * NWI + w];
    }
    if (w < NWI) G2bits[i * NWI + w] = acc;
}

// --- B2 row u = OR over items(u) of G2 rows; rsB[u] = popcount --------------
__global__ __launch_bounds__(128)
void b2_or(const u32* __restrict__ G2bits, const u16* __restrict__ itemsU,
           const u32* __restrict__ cntU, u32* __restrict__ B2bits,
           float* __restrict__ rsB)
{
    __shared__ u32 ps[128];
    const int u = blockIdx.x;
    const int w = threadIdx.x;
    u32 n = cntU[u]; if (n > LSTR) n = LSTR;
    u32 acc = 0;
    for (u32 k = 0; k < n; ++k) {
        int i = itemsU[u * LSTR + k];
        if (w < NWI) acc |= G2bits[i * NWI + w];
    }
    if (w < NWI) B2bits[u * NWI + w] = acc;
    ps[w] = (w < NWI) ? (u32)__popc(acc) : 0u;
    __syncthreads();
    if (w < 64) {
        u32 s = ps[w] + ps[w + 64];
#pragma unroll
        for (int off = 32; off; off >>= 1) s += __shfl_down((int)s, off);
        if (w == 0) rsB[u] = (float)s;
    }
}

// --- fused degrees + scale + transpose (CSR counts + B2bitsT popcount) ------
__global__ __launch_bounds__(256)
void scale_transpose_deg(const float* __restrict__ U, const float* __restrict__ I,
                         const u32* __restrict__ cntU, const u32* __restrict__ cntI,
                         const float* __restrict__ rsB, const u32* __restrict__ B2bitsT,
                         float* __restrict__ dvu, float* __restrict__ D3, float* __restrict__ D4,
                         float* __restrict__ dvi, float* __restrict__ D1, float* __restrict__ D2,
                         u16* __restrict__ XuT, u16* __restrict__ XiT)
{
    __shared__ u16 t[64][65];
    __shared__ float dvl[64];
    __shared__ u32 pcs[64][4];
    const int tx = threadIdx.x, ty = threadIdx.y;
    const int tid = ty * 64 + tx;
    const int bx = blockIdx.x;
    const float* X; u16* outT; int M, m0;
    if (bx < NBU) {
        m0 = bx * 64;
        if (tid < 64) {
            float a = (float)cntU[m0 + tid], b = rsB[m0 + tid], tt = a + b;
            float dv = tt > 0.f ? 1.0f / sqrtf(tt) : 0.f;
            dvu[m0 + tid] = dv;
            D3[m0 + tid]  = a > 0.f ? 1.0f / a : 0.f;
            D4[m0 + tid]  = b > 0.f ? 1.0f / b : 0.f;
            dvl[tid] = dv;
        }
        X = U; outT = XuT; M = NUu;
    } else {
        m0 = (bx - NBU) * 64;
        {   // csB[row] = popc(B2bitsT row), 4 threads per row
            int r = tid >> 2, q = tid & 3;
            const u32* rb = B2bitsT + (size_t)(m0 + r) * NWU + q * 32;
            u32 sb = 0;
            for (int k = 0; k < 32; ++k) sb += __popc(rb[k]);
            pcs[r][q] = sb;
        }
        __syncthreads();
        if (tid < 64) {
            float b = (float)(pcs[tid][0] + pcs[tid][1] + pcs[tid][2] + pcs[tid][3]);
            float a = (float)cntI[m0 + tid], tt = a + b;
            float dv = tt > 0.f ? 1.0f / sqrtf(tt) : 0.f;
            dvi[m0 + tid] = dv;
            D1[m0 + tid]  = a > 0.f ? 1.0f / a : 0.f;
            D2[m0 + tid]  = b > 0.f ? 1.0f / b : 0.f;
            dvl[tid] = dv;
        }
        X = I; outT = XiT; M = NIi;
    }
    __syncthreads();
#pragma unroll
    for (int i = 0; i < 16; ++i) {
        int row = i * 4 + ty;
        t[row][tx] = f2bf(X[(size_t)(m0 + row) * 64 + tx] * dvl[row]);
    }
    __syncthreads();
#pragma unroll
    for (int i = 0; i < 16; ++i) {
        int d = i * 4 + ty;
        outT[(size_t)d * M + m0 + tx] = t[tx][d];
    }
}

// --- skinny4<SAME>: both binary matrices per block, LDS-staged X, bf16 part -
// SAME=1 (hop1): Xa==Xb -> stage once, two accs, write part z=0 (H), z=1 (B2).
// SAME=0 (hop2): stage Xa and Xb, ONE acc = H·Xa + B2·Xb, write part z=0.
template <int SAME>
__global__ __launch_bounds__(256)
void skinny4(const u32* __restrict__ MbtH, const u32* __restrict__ MbtB,
             const u32* __restrict__ MbH,  const u32* __restrict__ MbB,
             const u16* __restrict__ X0a, const u16* __restrict__ X0b,
             const u16* __restrict__ X1a, const u16* __restrict__ X1b,
             u16* __restrict__ partI, u16* __restrict__ partU)
{
    constexpr int NX = SAME ? 1 : 2;
    __shared__ __align__(16) char lB[2][NX][16384];
    const int tid = threadIdx.x, lane = tid & 63, w = tid >> 6;
    const int sk = blockIdx.y;
    const int bx = blockIdx.x;
    const u32* MbA; const u32* MbBm; const u16* Xa; const u16* Xb; u16* part;
    int M, K, nw, m0;
    if (bx < NBI) {
        M = NIi; K = NUu; nw = NWU; m0 = bx * 64;
        MbA = MbtH; MbBm = MbtB; Xa = X0a; Xb = X0b; part = partI;
    } else {
        M = NUu; K = NIi; nw = NWI; m0 = (bx - NBI) * 64;
        MbA = MbH; MbBm = MbB; Xa = X1a; Xb = X1b; part = partU;
    }
    const int Kb = K / SKs, kBeg = sk * Kb, nc = Kb >> 7;   // chunks of 128 k

    const int st_row = tid >> 4;
    const int st_colb = (tid & 15) * 16;
    const char* Xac = (const char*)Xa;
    const char* Xbc = (const char*)Xb;
    const size_t rowstride = (size_t)K * 2;

    f32x4_t accH[4], accB[4];
#pragma unroll
    for (int j = 0; j < 4; ++j) {
        accH[j] = (f32x4_t){0.f, 0.f, 0.f, 0.f};
        accB[j] = (f32x4_t){0.f, 0.f, 0.f, 0.f};
    }

    const int q8 = (lane >> 4) * 8;
    const int rd15 = lane & 15;
    const int swz = (rd15 & 7) << 4;
    const int cb_base = (lane >> 4) * 16;
    const u32* rwH = MbA  + (size_t)(m0 + w * 16 + rd15) * nw + (kBeg >> 5);
    const u32* rwB = MbBm + (size_t)(m0 + w * 16 + rd15) * nw + (kBeg >> 5);

#define STAGE(buf, c)                                                          \
    {                                                                          \
        size_t kb2 = ((size_t)kBeg + (size_t)(c) * 128) * 2;                   \
        _Pragma("unroll")                                                      \
        for (int r = 0; r < 4; ++r) {                                          \
            int row = r * 16 + st_row;                                         \
            int scol = st_colb ^ ((row & 7) << 4);                             \
            size_t src = (size_t)row * rowstride + kb2 + scol;                 \
            gload16(Xac + src, &lB[buf][0][r * 4096 + tid * 16]);              \
            if (!SAME) gload16(Xbc + src, &lB[buf][NX - 1][r * 4096 + tid * 16]); \
        }                                                                      \
    }

    STAGE(0, 0);
    __syncthreads();
    for (int c = 0; c < nc; ++c) {
        const int buf = c & 1;
        if (c + 1 < nc) STAGE(buf ^ 1, c + 1);
        u32x4_t wvH = *(const u32x4_t*)(rwH + c * 4);
        u32x4_t wvB = *(const u32x4_t*)(rwB + c * 4);
#pragma unroll
        for (int s = 0; s < 4; ++s) {
            u32 byH = (wvH[s] >> q8) & 0xffu;
            u32 byB = (wvB[s] >> q8) & 0xffu;
            union { bf16x8_t v; u32 w[4]; } aH, aB;
#pragma unroll
            for (int i = 0; i < 4; ++i) {
                aH.w[i] = (((byH >> (2 * i)) & 1u) ? 0x3F80u : 0u)
                        | (((byH >> (2 * i + 1)) & 1u) ? 0x3F800000u : 0u);
                aB.w[i] = (((byB >> (2 * i)) & 1u) ? 0x3F80u : 0u)
                        | (((byB >> (2 * i + 1)) & 1u) ? 0x3F800000u : 0u);
            }
#pragma unroll
            for (int j = 0; j < 4; ++j) {
                int off = (rd15 + j * 16) * 256 + ((s * 64 + cb_base) ^ swz);
                bf16x8_t b0 = *(const bf16x8_t*)(&lB[buf][0][off]);
                if (SAME) {
                    accH[j] = __builtin_amdgcn_mfma_f32_16x16x32_bf16(aH.v, b0, accH[j], 0, 0, 0);
                    accB[j] = __builtin_amdgcn_mfma_f32_16x16x32_bf16(aB.v, b0, accB[j], 0, 0, 0);
                } else {
                    bf16x8_t b1 = *(const bf16x8_t*)(&lB[buf][NX - 1][off]);
                    accH[j] = __builtin_amdgcn_mfma_f32_16x16x32_bf16(aH.v, b0, accH[j], 0, 0, 0);
                    accH[j] = __builtin_amdgcn_mfma_f32_16x16x32_bf16(aB.v, b1, accH[j], 0, 0, 0);
                }
            }
        }
        __syncthreads();
    }
#undef STAGE

    const int rg = (lane >> 4) * 4;
    u16* oH = part + ((size_t)sk * M + m0 + w * 16 + rg) * 64;
#pragma unroll
    for (int j = 0; j < 4; ++j)
#pragma unroll
        for (int r = 0; r < 4; ++r)
            oH[(size_t)r * 64 + j * 16 + rd15] = f2bf(accH[j][r]);
    if (SAME) {
        u16* oB = part + ((size_t)(SKs + sk) * M + m0 + w * 16 + rg) * 64;
#pragma unroll
        for (int j = 0; j < 4; ++j)
#pragma unroll
            for (int r = 0; r < 4; ++r)
                oB[(size_t)r * 64 + j * 16 + rd15] = f2bf(accB[j][r]);
    }
}

// --- reduce bf16 partials, scale, write bf16 transposed (hop1) --------------
__global__ __launch_bounds__(256)
void reduce_T2(const u16* __restrict__ partI, const u16* __restrict__ partU,
               const float* __restrict__ D1, const float* __restrict__ D2,
               const float* __restrict__ D3, const float* __restrict__ D4,
               u16* __restrict__ TaT, u16* __restrict__ TbT,
               u16* __restrict__ SaT, u16* __restrict__ SbT)
{
    __shared__ u16 t[64][65];
    const int tx = threadIdx.x, ty = threadIdx.y;
    const int bx = blockIdx.x, z = blockIdx.y;
    const u16* part; const float* rs; u16* out; int M, m0;
    if (bx < NBI) { M = NIi; m0 = bx * 64;        part = partI; rs = z ? D2 : D1; out = z ? TbT : TaT; }
    else          { M = NUu; m0 = (bx - NBI) * 64; part = partU; rs = z ? D4 : D3; out = z ? SbT : SaT; }
#pragma unroll
    for (int i = 0; i < 16; ++i) {
        int row = i * 4 + ty;
        int m = m0 + row;
        float s = 0.f;
#pragma unroll
        for (int sk = 0; sk < SKs; ++sk)
            s += bf2f(part[((size_t)(z * SKs + sk) * M + m) * 64 + tx]);
        t[row][tx] = f2bf(s * rs[m]);
    }
    __syncthreads();
#pragma unroll
    for (int i = 0; i < 16; ++i) {
        int d = i * 4 + ty;
        out[(size_t)d * M + m0 + tx] = t[tx][d];
    }
}

// --- fused reduce_Z + final GEMM: out = (dv⊙Σ_sk part + X0)·W + bias --------
__global__ __launch_bounds__(256)
void final2(const u16* __restrict__ partU, const u16* __restrict__ partI,
            const float* __restrict__ U, const float* __restrict__ I,
            const float* __restrict__ dvu, const float* __restrict__ dvi,
            const float* __restrict__ W, const float* __restrict__ bias,
            float* __restrict__ Uout, float* __restrict__ Iout)
{
    __shared__ float Wl[4096];
    __shared__ float Zl[64][65];
    const int tx = threadIdx.x, ty = threadIdx.y;
    const int bx = blockIdx.x;
    const u16* part; const float* X0; const float* dv; float* out; int M, m0;
    if (bx < NBU) { M = NUu; m0 = bx * 64;        part = partU; X0 = U; dv = dvu; out = Uout; }
    else          { M = NIi; m0 = (bx - NBU) * 64; part = partI; X0 = I; dv = dvi; out = Iout; }
    const int t = ty * 64 + tx;
    for (int i = t; i < 4096; i += 256) Wl[i] = W[i];
    for (int r = ty; r < 64; r += 4) {
        int m = m0 + r;
        float s = 0.f;
#pragma unroll
        for (int s8 = 0; s8 < SKs; ++s8)
            s += bf2f(part[((size_t)s8 * M + m) * 64 + tx]);
        Zl[r][tx] = dv[m] * s + X0[(size_t)m * 64 + tx];
    }
    __syncthreads();
    float acc[16];
#pragma unroll
    for (int rr = 0; rr < 16; ++rr) acc[rr] = 0.f;
    for (int e = 0; e < 64; ++e) {
        float wv = Wl[e * 64 + tx];
#pragma unroll
        for (int rr = 0; rr < 16; ++rr)
            acc[rr] += Zl[ty * 16 + rr][e] * wv;
    }
    float bv = bias[tx];
#pragma unroll
    for (int rr = 0; rr < 16; ++rr)
        out[(size_t)(m0 + ty * 16 + rr) * 64 + tx] = acc[rr] + bv;
}

extern "C" void kernel_launch(void* const* d_in, const int* in_sizes, int n_in,
                              void* d_out, int out_size, void* d_ws, size_t ws_size,
                              hipStream_t stream)
{
    (void)in_sizes; (void)n_in; (void)out_size;
    const float* H  = (const float*)d_in[0];
    const float* U  = (const float*)d_in[1];
    const float* I  = (const float*)d_in[2];
    const float* W  = (const float*)d_in[3];
    const float* bs = (const float*)d_in[4];
    float* Uout = (float*)d_out;
    float* Iout = (float*)d_out + (size_t)NUu * 64;

    char* ws = (char*)d_ws;
    size_t off = 0;
    auto alloc = [&](size_t bytes) -> char* {
        char* p = ws + off;
        off += (bytes + 255) & ~(size_t)255;
        return p;
    };
    u32* Hbits   = (u32*)alloc((size_t)NUu * NWI * 4);
    u32* HbitsT  = (u32*)alloc((size_t)NIi * NWU * 4);
    u32* G2bits  = (u32*)alloc((size_t)NIi * NWI * 4);
    u32* B2bits  = (u32*)alloc((size_t)NUu * NWI * 4);
    u32* B2bitsT = (u32*)alloc((size_t)NIi * NWU * 4);
    u16* itemsU  = (u16*)alloc((size_t)NUu * LSTR * 2);
    u16* usersI  = (u16*)alloc((size_t)NIi * LSTR * 2);
    u16* partU   = (u16*)alloc((size_t)2 * SKs * NUu * 64 * 2);
    u16* partI   = (u16*)alloc((size_t)2 * SKs * NIi * 64 * 2);
    u16* XuT = (u16*)alloc((size_t)64 * NUu * 2);
    u16* XiT = (u16*)alloc((size_t)64 * NIi * 2);
    u16* TaT = (u16*)alloc((size_t)64 * NIi * 2);
    u16* TbT = (u16*)alloc((size_t)64 * NIi * 2);
    u16* SaT = (u16*)alloc((size_t)64 * NUu * 2);
    u16* SbT = (u16*)alloc((size_t)64 * NUu * 2);
    u32* cntU = (u32*)alloc(NUu * 4);
    u32* cntI = (u32*)alloc(NIi * 4);
    float* rsB = (float*)alloc(NUu * 4);
    float* dvu = (float*)alloc(NUu * 4);
    float* D3  = (float*)alloc(NUu * 4);
    float* D4  = (float*)alloc(NUu * 4);
    float* dvi = (float*)alloc(NIi * 4);
    float* D1  = (float*)alloc(NIi * 4);
    float* D2  = (float*)alloc(NIi * 4);
    if (off > ws_size) return;  // workspace too small: fail loudly

    dim3 b64x4(64, 4);

    // 1) pack H rows to bits (streaming)
    pack_rows<<<NUu * NWI / 256, 256, 0, stream>>>(H, Hbits);
    // 2) HbitsT = bit-transpose(Hbits)
    bit_transpose<<<dim3(NBI, NBU), b64x4, 0, stream>>>(Hbits, HbitsT, NWI, NWU);
    // 3) CSR lists + degree counts, both sides, atomic-free
    csr_build2<<<NUu / 4 + NIi / 4, 256, 0, stream>>>(Hbits, HbitsT, itemsU, usersI, cntU, cntI);
    // 4) G2 = (HᵀH > 0) bit rows
    g2_or<<<NIi, 128, 0, stream>>>(Hbits, usersI, cntI, G2bits);
    // 5) B2 = (H·G2 > 0) bit rows + rsB
    b2_or<<<NUu, 128, 0, stream>>>(G2bits, itemsU, cntU, B2bits, rsB);
    // 6) B2bitsT = bit-transpose(B2bits)
    bit_transpose<<<dim3(NBI, NBU), b64x4, 0, stream>>>(B2bits, B2bitsT, NWI, NWU);
    // 7) degrees + scale + transpose, fused (CSR counts + B2bitsT popcounts)
    scale_transpose_deg<<<NBU + NBI, b64x4, 0, stream>>>(
        U, I, cntU, cntI, rsB, B2bitsT, dvu, D3, D4, dvi, D1, D2, XuT, XiT);
    // 8) hop 1: partI = {HᵀXu, B2ᵀXu}, partU = {HXi, B2Xi} (shared X staging)
    skinny4<1><<<dim3(NBI + NBU, SKs), 256, 0, stream>>>(
        HbitsT, B2bitsT, Hbits, B2bits, XuT, XuT, XiT, XiT, partI, partU);
    // 9) T1/T2 (items, D1/D2) and S1/S2 (users, D3/D4), bf16 transposed
    reduce_T2<<<dim3(NBI + NBU, 2), b64x4, 0, stream>>>(
        partI, partU, D1, D2, D3, D4, TaT, TbT, SaT, SbT);
    // 10) hop 2: partI = HᵀS1 + B2ᵀS2, partU = HT1 + B2T2 (summed in-reg)
    skinny4<0><<<dim3(NBI + NBU, SKs), 256, 0, stream>>>(
        HbitsT, B2bitsT, Hbits, B2bits, SaT, SbT, TaT, TbT, partI, partU);
    // 11) fused reduce + output GEMM, both sides
    final2<<<NBU + NBI, b64x4, 0, stream>>>(
        partU, partI, U, I, dvu, dvi, W, bs, Uout, Iout);
}